// Round 3
// baseline (5066.581 us; speedup 1.0000x reference)
//
#include <hip/hip_runtime.h>
#include <stdint.h>

// TreeRNN: T=256 steps, D=512 rows, H=E=256, V=8192.
// 256 blocks (16 row-groups x 16 col-slices), plain launch (grid=256=#CUs,
// launch_bounds(256,1) => all blocks resident; sync cannot starve -- verified R2).
// Weights stay register-resident as MFMA B-fragments. Per step critical chain:
// gates -> bf16 exchange stores -> per-wave RELEASE flag -> peers ballot-poll 64
// flags -> 8x u64 agent gather (bf16, MFMA-ready) -> hh-GEMM -> gates.
// Off-chain: ih-GEMM (before poll), emb prefetch (after release), outs written
// coalesced by slice-0 blocks from their gather registers.

#define TT   256
#define DDIM 512
#define LSTR 264   // LDS row stride in bf16 elems (256 + 8 pad)

typedef float    float4v __attribute__((ext_vector_type(4)));
typedef short    short8  __attribute__((ext_vector_type(8)));
typedef uint32_t uint4v  __attribute__((ext_vector_type(4)));
typedef uint64_t ulong2v __attribute__((ext_vector_type(2)));

__device__ __forceinline__ unsigned short f2bf(float f){
  uint32_t u = __float_as_uint(f);
  u += 0x7fffu + ((u >> 16) & 1u);          // RNE, finite inputs
  return (unsigned short)(u >> 16);
}
__device__ __forceinline__ float bf2f(unsigned short h){
  return __uint_as_float(((uint32_t)h) << 16);
}

__global__ __launch_bounds__(256, 1)
void treernn_main(const int* __restrict__ nodes,
                  const unsigned char* __restrict__ edges,
                  const unsigned char* __restrict__ hinit,
                  const unsigned char* __restrict__ emb,
                  const unsigned char* __restrict__ cWih, const unsigned char* __restrict__ cWhh,
                  const unsigned char* __restrict__ cbih, const unsigned char* __restrict__ cbhh,
                  const unsigned char* __restrict__ sWih, const unsigned char* __restrict__ sWhh,
                  const unsigned char* __restrict__ sbih, const unsigned char* __restrict__ sbhh,
                  unsigned char* __restrict__ out,
                  unsigned char* __restrict__ ws)
{
  __shared__ __align__(16) unsigned short xs[2][32 * LSTR];  // x tiles (bf16), dbuf
  __shared__ __align__(16) unsigned short hstg[32 * LSTR];   // h_t (bf16) for MFMA A
  __shared__ float hnewstg[32 * 17];                         // fp32 state carry (own slice)
  __shared__ int det[8];

  const int tid   = threadIdx.x;
  const int lane  = tid & 63;
  const int wv    = tid >> 6;
  const int gru   = wv >> 1;        // 0 = child GRU, 1 = sibling GRU
  const int mtile = wv & 1;         // 16-row half of the 32-row group
  const int quad  = lane >> 4;
  const int l16   = lane & 15;

  const int g     = blockIdx.x >> 4;        // rows [g*32, g*32+32)
  const int slice = blockIdx.x & 15;        // cols [slice*16, +16)
  const int col   = slice * 16 + l16;
  const int d0    = g * 32;
  const int rowb  = mtile * 16 + quad * 4;  // C/D layout: row = quad*4 + reg

  // ---------------- runtime dtype detection (worked in R2, keep verbatim) ----------------
  if (tid < 8) det[tid] = 0;
  __syncthreads();
  {
    const unsigned short* hu = (const unsigned short*)hinit;
    int ce = 0;
    for (int i = tid; i < 4096; i += 256){
      const int e = (hu[i] >> 7) & 0xFF;
      ce += (e >= 100 && e <= 130) ? 1 : 0;
    }
    atomicAdd(&det[0], ce);
    const uint32_t* ewp = (const uint32_t*)edges;
    int b01 = 0, w01 = 0, wf = 0, hb = 0;
    for (int i = tid; i < 512; i += 256){
      const uint32_t w = ewp[i];
      w01 += (w <= 1u) ? 1 : 0;
      wf  += (w == 0u || w == 0x3F800000u) ? 1 : 0;
      const uint32_t h0 = w & 0xFFFFu, h1 = w >> 16;
      hb  += ((h0 == 0u || h0 == 0x3F80u) ? 1 : 0) + ((h1 == 0u || h1 == 0x3F80u) ? 1 : 0);
      b01 += (((w      ) & 0xFFu) <= 1u ? 1 : 0) + (((w >> 8 ) & 0xFFu) <= 1u ? 1 : 0)
           + (((w >> 16) & 0xFFu) <= 1u ? 1 : 0) + (((w >> 24)        ) <= 1u ? 1 : 0);
    }
    atomicAdd(&det[1], b01); atomicAdd(&det[2], w01);
    atomicAdd(&det[3], wf);  atomicAdd(&det[4], hb);
  }
  __syncthreads();
  const int fdt = (det[0] >= 3480) ? 1 : 0;   // 1 = floats are bf16
  int efmt;                                    // 0=u8, 1=i32, 2=f32, 3=bf16
  if      (det[2] == 512)  efmt = 1;
  else if (det[1] == 2048) efmt = 0;
  else if (det[4] == 1024) efmt = 3;
  else if (det[3] == 512)  efmt = 2;
  else                     efmt = 0;

  uint32_t*       flg = (uint32_t*)ws;                 // [16 groups][64 wave-flags]
  unsigned short* xb  = (unsigned short*)(ws + 8192);  // exchange: [2][512][256] bf16

  const unsigned char* Wihp = gru ? sWih : cWih;
  const unsigned char* Whhp = gru ? sWhh : cWhh;
  const unsigned char* bihp = gru ? sbih : cbih;
  const unsigned char* bhhp = gru ? sbhh : cbhh;

  float bI[3], bH[3];
  #pragma unroll
  for (int ga = 0; ga < 3; ++ga){
    if (fdt){
      bI[ga] = bf2f(((const unsigned short*)bihp)[ga * 256 + col]);
      bH[ga] = bf2f(((const unsigned short*)bhhp)[ga * 256 + col]);
    } else {
      bI[ga] = ((const float*)bihp)[ga * 256 + col];
      bH[ga] = ((const float*)bhhp)[ga * 256 + col];
    }
  }

  // Weight slices -> bf16 MFMA B-fragments (lane: B[k=quad*8+j][n=l16], row-major W).
  short8 wI[3][8], wH[3][8];
  for (int ga = 0; ga < 3; ++ga){
    const int rw = ga * 256 + col;
    for (int kc = 0; kc < 8; ++kc){
      const int ke = kc * 32 + quad * 8;
      if (fdt){
        wI[ga][kc] = *(const short8*)((const unsigned short*)Wihp + (size_t)rw * 256 + ke);
        wH[ga][kc] = *(const short8*)((const unsigned short*)Whhp + (size_t)rw * 256 + ke);
      } else {
        const float* pI = (const float*)Wihp + (size_t)rw * 256 + ke;
        const float* pH = (const float*)Whhp + (size_t)rw * 256 + ke;
        short8 va, vb;
        #pragma unroll
        for (int j = 0; j < 8; ++j){ va[j] = (short)f2bf(pI[j]); vb[j] = (short)f2bf(pH[j]); }
        wI[ga][kc] = va; wH[ga][kc] = vb;
      }
    }
  }

  // Stage x_0 and h_0: thread -> row tid>>3, 32 cols from (tid&7)*32
  {
    const int r = tid >> 3, c8 = (tid & 7) * 32;
    const int node = nodes[d0 + r];
    unsigned short* xdst = &xs[0][r * LSTR + c8];
    unsigned short* hdst = &hstg[r * LSTR + c8];
    if (fdt){
      const uint4v* sx = (const uint4v*)((const unsigned short*)emb   + (size_t)node * 256 + c8);
      const uint4v* sh = (const uint4v*)((const unsigned short*)hinit + (size_t)(d0 + r) * 256 + c8);
      #pragma unroll
      for (int j = 0; j < 4; ++j){ ((uint4v*)xdst)[j] = sx[j]; ((uint4v*)hdst)[j] = sh[j]; }
    } else {
      const float* sx = (const float*)emb   + (size_t)node * 256 + c8;
      const float* sh = (const float*)hinit + (size_t)(d0 + r) * 256 + c8;
      #pragma unroll
      for (int q = 0; q < 4; ++q){
        short8 vx, vh;
        #pragma unroll
        for (int j = 0; j < 8; ++j){ vx[j] = (short)f2bf(sx[q*8+j]); vh[j] = (short)f2bf(sh[q*8+j]); }
        *(short8*)&xdst[q * 8] = vx;
        *(short8*)&hdst[q * 8] = vh;
      }
    }
  }

  // edges for t=0
  int ef[4];
  {
    const int base = d0 + rowb;
    if (efmt == 0){      for (int r = 0; r < 4; ++r) ef[r] = edges[base + r] != 0; }
    else if (efmt == 1){ for (int r = 0; r < 4; ++r) ef[r] = ((const int*)edges)[base + r] != 0; }
    else if (efmt == 3){ for (int r = 0; r < 4; ++r) ef[r] = ((const unsigned short*)edges)[base + r] != 0; }
    else {               for (int r = 0; r < 4; ++r) ef[r] = ((const float*)edges)[base + r] != 0.0f; }
  }
  __syncthreads();

  uint64_t gv[8];   // gathered h_t (bf16x4 per u64), reused for out-write

  for (int t = 0; t < TT; ++t){
    // ---- ih-GEMM on staged x_t (peer-independent: runs before the poll) ----
    float4v aI[3], aH[3];
    #pragma unroll
    for (int ga = 0; ga < 3; ++ga) aI[ga] = (float4v){bI[ga], bI[ga], bI[ga], bI[ga]};
    {
      const unsigned short* xc = xs[t & 1];
      #pragma unroll
      for (int kc = 0; kc < 8; ++kc){
        short8 a = *(const short8*)&xc[(mtile * 16 + l16) * LSTR + kc * 32 + quad * 8];
        #pragma unroll
        for (int ga = 0; ga < 3; ++ga)
          aI[ga] = __builtin_amdgcn_mfma_f32_16x16x32_bf16(a, wI[ga][kc], aI[ga], 0, 0, 0);
      }
    }

    // ---- fp32 state carry (read before B1; writes happen after B1) ----
    float hold[4];
    if (t == 0){
      #pragma unroll
      for (int r = 0; r < 4; ++r){
        const size_t idx = (size_t)(d0 + rowb + r) * 256 + col;
        hold[r] = fdt ? bf2f(((const unsigned short*)hinit)[idx]) : ((const float*)hinit)[idx];
      }
    } else {
      #pragma unroll
      for (int r = 0; r < 4; ++r) hold[r] = hnewstg[(rowb + r) * 17 + l16];
    }

    // ---- poll 64 per-wave flags (ballot), then gather h_t (bf16, MFMA-ready) ----
    if (t > 0){
      const uint32_t target = (uint32_t)t;
      const uint32_t* fp = flg + g * 64 + lane;
      uint32_t fv = __hip_atomic_load(fp, __ATOMIC_RELAXED, __HIP_MEMORY_SCOPE_AGENT);
      int guard = 0;
      while (__ballot(fv < target) != 0ull){
        __builtin_amdgcn_s_sleep(1);
        fv = __hip_atomic_load(fp, __ATOMIC_RELAXED, __HIP_MEMORY_SCOPE_AGENT);
        if (++guard > (1 << 17)) break;   // bounded: broken sync -> garbage, not hang
      }
      __atomic_signal_fence(__ATOMIC_SEQ_CST);
      const int r = tid >> 3, c8 = (tid & 7) * 32;
      const uint64_t* src = (const uint64_t*)(xb + (size_t)(t & 1) * 131072
                                                 + (size_t)(d0 + r) * 256 + c8);
      #pragma unroll
      for (int k = 0; k < 8; ++k)
        gv[k] = __hip_atomic_load(src + k, __ATOMIC_RELAXED, __HIP_MEMORY_SCOPE_AGENT);
      ulong2v* dst = (ulong2v*)&hstg[r * LSTR + c8];
      #pragma unroll
      for (int k = 0; k < 4; ++k){ ulong2v v2; v2[0] = gv[2*k]; v2[1] = gv[2*k+1]; dst[k] = v2; }
    }
    __syncthreads();   // B1: hstg ready; also separates hold-reads from hnewstg writes

    // ---- hh-GEMM ----
    #pragma unroll
    for (int ga = 0; ga < 3; ++ga) aH[ga] = (float4v){bH[ga], bH[ga], bH[ga], bH[ga]};
    #pragma unroll
    for (int kc = 0; kc < 8; ++kc){
      short8 a = *(const short8*)&hstg[(mtile * 16 + l16) * LSTR + kc * 32 + quad * 8];
      #pragma unroll
      for (int ga = 0; ga < 3; ++ga)
        aH[ga] = __builtin_amdgcn_mfma_f32_16x16x32_bf16(a, wH[ga][kc], aH[ga], 0, 0, 0);
    }

    // ---- gates ----
    float hnv[4]; int mine[4];
    #pragma unroll
    for (int r = 0; r < 4; ++r){
      const float pr = aI[0][r] + aH[0][r];
      const float pz = aI[1][r] + aH[1][r];
      const float R  = 1.0f / (1.0f + exp2f(-1.4426950408889634f * pr));
      const float Z  = 1.0f / (1.0f + exp2f(-1.4426950408889634f * pz));
      float ag = aI[2][r] + R * aH[2][r];
      ag = fminf(30.0f, fmaxf(-30.0f, ag));
      const float ex = exp2f(-2.8853900817779268f * ag);
      const float N  = (1.0f - ex) / (1.0f + ex);
      hnv[r]  = N + Z * (hold[r] - N);
      mine[r] = ((ef[r] != 0) == (gru == 0)) ? 1 : 0;   // edge -> child GRU
    }

    // ---- local fp32 carry + bf16 exchange stores (packed u32 via shfl pairs) ----
    #pragma unroll
    for (int r = 0; r < 4; ++r){
      if (mine[r]) hnewstg[(rowb + r) * 17 + l16] = hnv[r];
      const uint32_t bb = (uint32_t)f2bf(hnv[r]);
      const uint32_t ob = (uint32_t)__shfl_xor((int)bb, 1, 64);
      if (mine[r] && !(lane & 1)){
        unsigned short* p = xb + (size_t)((t + 1) & 1) * 131072
                               + (size_t)(d0 + rowb + r) * 256 + col;   // col even
        __hip_atomic_store((uint32_t*)p, bb | (ob << 16),
                           __ATOMIC_RELAXED, __HIP_MEMORY_SCOPE_AGENT);
      }
    }

    // ---- per-wave RELEASE flag: vmcnt(0) covers only this wave's work so far ----
    if (lane == 0)
      __hip_atomic_store(flg + g * 64 + slice * 4 + wv, (uint32_t)(t + 1),
                         __ATOMIC_RELEASE, __HIP_MEMORY_SCOPE_AGENT);

    // ---- slice-0 writes out[t-1] from gather regs (coalesced full lines, off-chain) ----
    if (slice == 0 && t > 0){
      const int r = tid >> 3, c8 = (tid & 7) * 32;
      if (fdt){
        uint64_t* od = (uint64_t*)((unsigned short*)out + (size_t)(t - 1) * 131072
                                   + (size_t)(d0 + r) * 256 + c8);
        #pragma unroll
        for (int k = 0; k < 8; ++k) __builtin_nontemporal_store(gv[k], od + k);
      } else {
        float* od = (float*)out + (size_t)(t - 1) * 131072 + (size_t)(d0 + r) * 256 + c8;
        #pragma unroll
        for (int k = 0; k < 8; ++k){
          float4v f;
          #pragma unroll
          for (int j = 0; j < 4; ++j) f[j] = bf2f((unsigned short)(gv[k] >> (16 * j)));
          __builtin_nontemporal_store(f, (float4v*)od + k);
        }
      }
    }

    // ---- prefetch x_{t+1} + edges_{t+1} (after release: off the publish chain) ----
    if (t < TT - 1){
      const int r = tid >> 3, c8 = (tid & 7) * 32;
      const int node = nodes[(t + 1) * DDIM + d0 + r];
      unsigned short* dst = &xs[(t + 1) & 1][r * LSTR + c8];
      if (fdt){
        const uint4v* s = (const uint4v*)((const unsigned short*)emb + (size_t)node * 256 + c8);
        uint4v rv[4];
        #pragma unroll
        for (int j = 0; j < 4; ++j) rv[j] = s[j];
        #pragma unroll
        for (int j = 0; j < 4; ++j) ((uint4v*)dst)[j] = rv[j];
      } else {
        const float* s = (const float*)emb + (size_t)node * 256 + c8;
        float4v rv[8];
        #pragma unroll
        for (int j = 0; j < 8; ++j) rv[j] = ((const float4v*)s)[j];
        #pragma unroll
        for (int q = 0; q < 4; ++q){
          short8 v;
          #pragma unroll
          for (int j = 0; j < 8; ++j){ const int e2 = q*8+j; v[j] = (short)f2bf(rv[e2>>2][e2&3]); }
          *(short8*)&dst[q * 8] = v;
        }
      }
      const int base = (t + 1) * DDIM + d0 + rowb;
      if (efmt == 0){      for (int r2 = 0; r2 < 4; ++r2) ef[r2] = edges[base + r2] != 0; }
      else if (efmt == 1){ for (int r2 = 0; r2 < 4; ++r2) ef[r2] = ((const int*)edges)[base + r2] != 0; }
      else if (efmt == 3){ for (int r2 = 0; r2 < 4; ++r2) ef[r2] = ((const unsigned short*)edges)[base + r2] != 0; }
      else {               for (int r2 = 0; r2 < 4; ++r2) ef[r2] = ((const float*)edges)[base + r2] != 0.0f; }
    }

    __syncthreads();   // B2: xs[t+1] ready; hstg reads done before next gather
  }

  // ---- epilogue: slice-0 blocks emit out[255] and h_final from h_256 ----
  if (slice == 0){
    const uint32_t* fp = flg + g * 64 + lane;
    uint32_t fv = __hip_atomic_load(fp, __ATOMIC_RELAXED, __HIP_MEMORY_SCOPE_AGENT);
    int guard = 0;
    while (__ballot(fv < 256u) != 0ull){
      __builtin_amdgcn_s_sleep(1);
      fv = __hip_atomic_load(fp, __ATOMIC_RELAXED, __HIP_MEMORY_SCOPE_AGENT);
      if (++guard > (1 << 17)) break;
    }
    __atomic_signal_fence(__ATOMIC_SEQ_CST);
    const int r = tid >> 3, c8 = (tid & 7) * 32;
    const uint64_t* src = (const uint64_t*)(xb + /* buf 256&1=0 */ (size_t)(d0 + r) * 256 + c8);
    uint64_t ev[8];
    #pragma unroll
    for (int k = 0; k < 8; ++k)
      ev[k] = __hip_atomic_load(src + k, __ATOMIC_RELAXED, __HIP_MEMORY_SCOPE_AGENT);
    if (fdt){
      unsigned short* o16 = (unsigned short*)out;
      uint64_t* o1 = (uint64_t*)(o16 + (size_t)255 * 131072 + (size_t)(d0 + r) * 256 + c8);
      uint64_t* o2 = (uint64_t*)(o16 + (size_t)256 * 131072 + (size_t)(d0 + r) * 256 + c8);
      #pragma unroll
      for (int k = 0; k < 8; ++k){
        __builtin_nontemporal_store(ev[k], o1 + k);
        __builtin_nontemporal_store(ev[k], o2 + k);
      }
    } else {
      float* o1 = (float*)out + (size_t)255 * 131072 + (size_t)(d0 + r) * 256 + c8;
      float* o2 = (float*)out + (size_t)256 * 131072 + (size_t)(d0 + r) * 256 + c8;
      #pragma unroll
      for (int k = 0; k < 8; ++k){
        float4v f;
        #pragma unroll
        for (int j = 0; j < 4; ++j) f[j] = bf2f((unsigned short)(ev[k] >> (16 * j)));
        __builtin_nontemporal_store(f, (float4v*)o1 + k);
        __builtin_nontemporal_store(f, (float4v*)o2 + k);
      }
    }
  }
}

extern "C" void kernel_launch(void* const* d_in, const int* in_sizes, int n_in,
                              void* d_out, int out_size, void* d_ws, size_t ws_size,
                              hipStream_t stream)
{
  const int*           nodes = (const int*)d_in[0];
  const unsigned char* edges = (const unsigned char*)d_in[1];
  const unsigned char* hinit = (const unsigned char*)d_in[2];
  const unsigned char* emb   = (const unsigned char*)d_in[3];
  const unsigned char* cWih  = (const unsigned char*)d_in[4];
  const unsigned char* cWhh  = (const unsigned char*)d_in[5];
  const unsigned char* cbih  = (const unsigned char*)d_in[6];
  const unsigned char* cbhh  = (const unsigned char*)d_in[7];
  const unsigned char* sWih  = (const unsigned char*)d_in[8];
  const unsigned char* sWhh  = (const unsigned char*)d_in[9];
  const unsigned char* sbih  = (const unsigned char*)d_in[10];
  const unsigned char* sbhh  = (const unsigned char*)d_in[11];
  (void)in_sizes; (void)n_in; (void)out_size; (void)ws_size;

  // zero flag region (ws re-poisoned 0xAA before every launch)
  hipMemsetAsync(d_ws, 0, 8192, stream);

  treernn_main<<<dim3(256), dim3(256), 0, stream>>>(
      nodes, edges, hinit, emb, cWih, cWhh, cbih, cbhh, sWih, sWhh, sbih, sbhh,
      (unsigned char*)d_out, (unsigned char*)d_ws);
}

// Round 4
// 1326.082 us; speedup vs baseline: 3.8207x; 3.8207x over previous
//
#include <hip/hip_runtime.h>
#include <stdint.h>

// TreeRNN: T=256 steps, D=512 rows, H=E=256, V=8192.
// 256 blocks (16 row-groups x 16 col-slices), plain launch (grid=256=#CUs,
// launch_bounds(256,1) => all blocks resident; verified R2/R3). Weights live in
// VGPRs as MFMA B-fragments. Per-step chain: gates -> bf16 exchange stores
// (agent-scope, L2-bypass) -> s_waitcnt vmcnt(0) -> RELAXED per-wave flag ->
// peers ballot-poll 64 flags -> interleaved full-line u64 gather -> hh-GEMM.
// R4 fixes vs R3: no RELEASE (avoids agent-release L2-writeback on gfx950);
// gather/out mapping gives per-instruction full-line coalescing; outs are plain
// cached stores issued at the TOP of the next iteration (ack during poll wait).

#define TT   256
#define DDIM 512
#define LSTR 264   // LDS row stride in bf16 elems (256 + 8 pad)

typedef float    float4v __attribute__((ext_vector_type(4)));
typedef short    short8  __attribute__((ext_vector_type(8)));
typedef uint32_t uint4v  __attribute__((ext_vector_type(4)));

__device__ __forceinline__ unsigned short f2bf(float f){
  uint32_t u = __float_as_uint(f);
  u += 0x7fffu + ((u >> 16) & 1u);          // RNE, finite inputs
  return (unsigned short)(u >> 16);
}
__device__ __forceinline__ float bf2f(unsigned short h){
  return __uint_as_float(((uint32_t)h) << 16);
}

__global__ __launch_bounds__(256, 1)
void treernn_main(const int* __restrict__ nodes,
                  const unsigned char* __restrict__ edges,
                  const unsigned char* __restrict__ hinit,
                  const unsigned char* __restrict__ emb,
                  const unsigned char* __restrict__ cWih, const unsigned char* __restrict__ cWhh,
                  const unsigned char* __restrict__ cbih, const unsigned char* __restrict__ cbhh,
                  const unsigned char* __restrict__ sWih, const unsigned char* __restrict__ sWhh,
                  const unsigned char* __restrict__ sbih, const unsigned char* __restrict__ sbhh,
                  unsigned char* __restrict__ out,
                  unsigned char* __restrict__ ws)
{
  __shared__ __align__(16) unsigned short xs[2][32 * LSTR];  // x tiles (bf16), dbuf
  __shared__ __align__(16) unsigned short hstg[32 * LSTR];   // h_t (bf16) for MFMA A
  __shared__ float hnewstg[32 * 17];                         // fp32 state carry (own slice)
  __shared__ int det[8];

  const int tid   = threadIdx.x;
  const int lane  = tid & 63;
  const int wv    = tid >> 6;
  const int gru   = wv >> 1;        // 0 = child GRU, 1 = sibling GRU
  const int mtile = wv & 1;         // 16-row half of the 32-row group
  const int quad  = lane >> 4;
  const int l16   = lane & 15;

  const int g     = blockIdx.x >> 4;        // rows [g*32, g*32+32)
  const int slice = blockIdx.x & 15;        // cols [slice*16, +16)
  const int col   = slice * 16 + l16;
  const int d0    = g * 32;
  const int rowb  = mtile * 16 + quad * 4;  // C/D layout: row = quad*4 + reg

  // ---------------- runtime dtype detection (verified R2/R3, verbatim) ----------------
  if (tid < 8) det[tid] = 0;
  __syncthreads();
  {
    const unsigned short* hu = (const unsigned short*)hinit;
    int ce = 0;
    for (int i = tid; i < 4096; i += 256){
      const int e = (hu[i] >> 7) & 0xFF;
      ce += (e >= 100 && e <= 130) ? 1 : 0;
    }
    atomicAdd(&det[0], ce);
    const uint32_t* ewp = (const uint32_t*)edges;
    int b01 = 0, w01 = 0, wf = 0, hb = 0;
    for (int i = tid; i < 512; i += 256){
      const uint32_t w = ewp[i];
      w01 += (w <= 1u) ? 1 : 0;
      wf  += (w == 0u || w == 0x3F800000u) ? 1 : 0;
      const uint32_t h0 = w & 0xFFFFu, h1 = w >> 16;
      hb  += ((h0 == 0u || h0 == 0x3F80u) ? 1 : 0) + ((h1 == 0u || h1 == 0x3F80u) ? 1 : 0);
      b01 += (((w      ) & 0xFFu) <= 1u ? 1 : 0) + (((w >> 8 ) & 0xFFu) <= 1u ? 1 : 0)
           + (((w >> 16) & 0xFFu) <= 1u ? 1 : 0) + (((w >> 24)        ) <= 1u ? 1 : 0);
    }
    atomicAdd(&det[1], b01); atomicAdd(&det[2], w01);
    atomicAdd(&det[3], wf);  atomicAdd(&det[4], hb);
  }
  __syncthreads();
  const int fdt = (det[0] >= 3480) ? 1 : 0;   // 1 = floats are bf16
  int efmt;                                    // 0=u8, 1=i32, 2=f32, 3=bf16
  if      (det[2] == 512)  efmt = 1;
  else if (det[1] == 2048) efmt = 0;
  else if (det[4] == 1024) efmt = 3;
  else if (det[3] == 512)  efmt = 2;
  else                     efmt = 0;

  uint32_t*       flg = (uint32_t*)ws;                 // [16 groups][64 wave-flags]
  unsigned short* xb  = (unsigned short*)(ws + 8192);  // exchange: [2][512][256] bf16

  const unsigned char* Wihp = gru ? sWih : cWih;
  const unsigned char* Whhp = gru ? sWhh : cWhh;
  const unsigned char* bihp = gru ? sbih : cbih;
  const unsigned char* bhhp = gru ? sbhh : cbhh;

  float bI[3], bH[3];
  #pragma unroll
  for (int ga = 0; ga < 3; ++ga){
    if (fdt){
      bI[ga] = bf2f(((const unsigned short*)bihp)[ga * 256 + col]);
      bH[ga] = bf2f(((const unsigned short*)bhhp)[ga * 256 + col]);
    } else {
      bI[ga] = ((const float*)bihp)[ga * 256 + col];
      bH[ga] = ((const float*)bhhp)[ga * 256 + col];
    }
  }

  // Weight slices -> bf16 MFMA B-fragments (lane: B[k=quad*8+j][n=l16], row-major W).
  short8 wI[3][8], wH[3][8];
  for (int ga = 0; ga < 3; ++ga){
    const int rw = ga * 256 + col;
    for (int kc = 0; kc < 8; ++kc){
      const int ke = kc * 32 + quad * 8;
      if (fdt){
        wI[ga][kc] = *(const short8*)((const unsigned short*)Wihp + (size_t)rw * 256 + ke);
        wH[ga][kc] = *(const short8*)((const unsigned short*)Whhp + (size_t)rw * 256 + ke);
      } else {
        const float* pI = (const float*)Wihp + (size_t)rw * 256 + ke;
        const float* pH = (const float*)Whhp + (size_t)rw * 256 + ke;
        short8 va, vb;
        #pragma unroll
        for (int j = 0; j < 8; ++j){ va[j] = (short)f2bf(pI[j]); vb[j] = (short)f2bf(pH[j]); }
        wI[ga][kc] = va; wH[ga][kc] = vb;
      }
    }
  }

  // Stage x_0 and h_0: thread -> row tid>>3, 32 cols from (tid&7)*32
  {
    const int r = tid >> 3, c8 = (tid & 7) * 32;
    const int node = nodes[d0 + r];
    unsigned short* xdst = &xs[0][r * LSTR + c8];
    unsigned short* hdst = &hstg[r * LSTR + c8];
    if (fdt){
      const uint4v* sx = (const uint4v*)((const unsigned short*)emb   + (size_t)node * 256 + c8);
      const uint4v* sh = (const uint4v*)((const unsigned short*)hinit + (size_t)(d0 + r) * 256 + c8);
      #pragma unroll
      for (int j = 0; j < 4; ++j){ ((uint4v*)xdst)[j] = sx[j]; ((uint4v*)hdst)[j] = sh[j]; }
    } else {
      const float* sx = (const float*)emb   + (size_t)node * 256 + c8;
      const float* sh = (const float*)hinit + (size_t)(d0 + r) * 256 + c8;
      #pragma unroll
      for (int q = 0; q < 4; ++q){
        short8 vx, vh;
        #pragma unroll
        for (int j = 0; j < 8; ++j){ vx[j] = (short)f2bf(sx[q*8+j]); vh[j] = (short)f2bf(sh[q*8+j]); }
        *(short8*)&xdst[q * 8] = vx;
        *(short8*)&hdst[q * 8] = vh;
      }
    }
  }

  // edges for t=0
  int ef[4];
  {
    const int base = d0 + rowb;
    if (efmt == 0){      for (int r = 0; r < 4; ++r) ef[r] = edges[base + r] != 0; }
    else if (efmt == 1){ for (int r = 0; r < 4; ++r) ef[r] = ((const int*)edges)[base + r] != 0; }
    else if (efmt == 3){ for (int r = 0; r < 4; ++r) ef[r] = ((const unsigned short*)edges)[base + r] != 0; }
    else {               for (int r = 0; r < 4; ++r) ef[r] = ((const float*)edges)[base + r] != 0.0f; }
  }
  __syncthreads();

  // gv: gathered h_t, interleaved mapping -- thread (row = tid>>3) owns u64-chunk
  // (tid&7) + k*8 of its row (chunk = 4 bf16). Per instruction k, each 8-lane octet
  // covers one full 64-B line => no partial-line traffic on the L2-bypass path.
  uint64_t gv[8];
  const int grow = tid >> 3;        // row within group for gather/out
  const int gchk = tid & 7;         // chunk lane offset

  for (int t = 0; t < TT; ++t){
    // ---- out[t-2] from last step's gather regs (plain cached stores; they ack
    //      into L2 during ih-GEMM + poll wait, off the publish path) ----
    if (slice == 0 && t >= 2){
      if (fdt){
        uint64_t* od = (uint64_t*)((unsigned short*)out + (size_t)(t - 2) * 131072
                                   + (size_t)(d0 + grow) * 256) + gchk;
        #pragma unroll
        for (int k = 0; k < 8; ++k) od[k * 8] = gv[k];
      } else {
        float* ob = (float*)out + (size_t)(t - 2) * 131072 + (size_t)(d0 + grow) * 256 + gchk * 4;
        #pragma unroll
        for (int k = 0; k < 8; ++k){
          float4v f;
          #pragma unroll
          for (int j = 0; j < 4; ++j) f[j] = bf2f((unsigned short)(gv[k] >> (16 * j)));
          *(float4v*)(ob + k * 32) = f;
        }
      }
    }

    // ---- ih-GEMM on staged x_t (peer-independent: runs before the poll) ----
    float4v aI[3], aH[3];
    #pragma unroll
    for (int ga = 0; ga < 3; ++ga) aI[ga] = (float4v){bI[ga], bI[ga], bI[ga], bI[ga]};
    {
      const unsigned short* xc = xs[t & 1];
      #pragma unroll
      for (int kc = 0; kc < 8; ++kc){
        short8 a = *(const short8*)&xc[(mtile * 16 + l16) * LSTR + kc * 32 + quad * 8];
        #pragma unroll
        for (int ga = 0; ga < 3; ++ga)
          aI[ga] = __builtin_amdgcn_mfma_f32_16x16x32_bf16(a, wI[ga][kc], aI[ga], 0, 0, 0);
      }
    }

    // ---- fp32 state carry (read before B1; writes happen after B1) ----
    float hold[4];
    if (t == 0){
      #pragma unroll
      for (int r = 0; r < 4; ++r){
        const size_t idx = (size_t)(d0 + rowb + r) * 256 + col;
        hold[r] = fdt ? bf2f(((const unsigned short*)hinit)[idx]) : ((const float*)hinit)[idx];
      }
    } else {
      #pragma unroll
      for (int r = 0; r < 4; ++r) hold[r] = hnewstg[(rowb + r) * 17 + l16];
    }

    // ---- poll 64 per-wave flags (ballot, relaxed), then full-line u64 gather ----
    if (t > 0){
      const uint32_t target = (uint32_t)t;
      const uint32_t* fp = flg + g * 64 + lane;
      uint32_t fv = __hip_atomic_load(fp, __ATOMIC_RELAXED, __HIP_MEMORY_SCOPE_AGENT);
      int guard = 0;
      while (__ballot(fv < target) != 0ull){
        __builtin_amdgcn_s_sleep(1);
        fv = __hip_atomic_load(fp, __ATOMIC_RELAXED, __HIP_MEMORY_SCOPE_AGENT);
        if (++guard > (1 << 17)) break;   // bounded: broken sync -> garbage, not hang
      }
      __atomic_signal_fence(__ATOMIC_SEQ_CST);
      const uint64_t* src = (const uint64_t*)(xb + (size_t)(t & 1) * 131072
                                                 + (size_t)(d0 + grow) * 256) + gchk;
      #pragma unroll
      for (int k = 0; k < 8; ++k)
        gv[k] = __hip_atomic_load(src + k * 8, __ATOMIC_RELAXED, __HIP_MEMORY_SCOPE_AGENT);
      unsigned short* dst = &hstg[grow * LSTR + gchk * 4];
      #pragma unroll
      for (int k = 0; k < 8; ++k) *(uint64_t*)&dst[k * 32] = gv[k];
    }
    __syncthreads();   // B1: hstg ready; separates hold-reads from hnewstg writes

    // ---- hh-GEMM ----
    #pragma unroll
    for (int ga = 0; ga < 3; ++ga) aH[ga] = (float4v){bH[ga], bH[ga], bH[ga], bH[ga]};
    #pragma unroll
    for (int kc = 0; kc < 8; ++kc){
      short8 a = *(const short8*)&hstg[(mtile * 16 + l16) * LSTR + kc * 32 + quad * 8];
      #pragma unroll
      for (int ga = 0; ga < 3; ++ga)
        aH[ga] = __builtin_amdgcn_mfma_f32_16x16x32_bf16(a, wH[ga][kc], aH[ga], 0, 0, 0);
    }

    // ---- gates ----
    float hnv[4]; int mine[4];
    #pragma unroll
    for (int r = 0; r < 4; ++r){
      const float pr = aI[0][r] + aH[0][r];
      const float pz = aI[1][r] + aH[1][r];
      const float R  = 1.0f / (1.0f + exp2f(-1.4426950408889634f * pr));
      const float Z  = 1.0f / (1.0f + exp2f(-1.4426950408889634f * pz));
      float ag = aI[2][r] + R * aH[2][r];
      ag = fminf(30.0f, fmaxf(-30.0f, ag));
      const float ex = exp2f(-2.8853900817779268f * ag);
      const float N  = (1.0f - ex) / (1.0f + ex);
      hnv[r]  = N + Z * (hold[r] - N);
      mine[r] = ((ef[r] != 0) == (gru == 0)) ? 1 : 0;   // edge -> child GRU
    }

    // ---- local fp32 carry + bf16 exchange stores (packed u32 via shfl pairs) ----
    #pragma unroll
    for (int r = 0; r < 4; ++r){
      if (mine[r]) hnewstg[(rowb + r) * 17 + l16] = hnv[r];
      const uint32_t bb = (uint32_t)f2bf(hnv[r]);
      const uint32_t ob = (uint32_t)__shfl_xor((int)bb, 1, 64);
      if (mine[r] && !(lane & 1)){
        unsigned short* p = xb + (size_t)((t + 1) & 1) * 131072
                               + (size_t)(d0 + rowb + r) * 256 + col;   // col even
        __hip_atomic_store((uint32_t*)p, bb | (ob << 16),
                           __ATOMIC_RELAXED, __HIP_MEMORY_SCOPE_AGENT);
      }
    }

    // ---- publish: wait ONLY this wave's stores to the coherence point, then a
    //      RELAXED flag store. No RELEASE => no agent-scope L2 writeback (R3 bug).
    //      Protocol identical to R2's empirically-correct syncthreads+relaxed-add.
    __atomic_signal_fence(__ATOMIC_SEQ_CST);
    __builtin_amdgcn_s_waitcnt(0x0F70);   // vmcnt(0), lgkm/exp don't-care
    __atomic_signal_fence(__ATOMIC_SEQ_CST);
    if (lane == 0)
      __hip_atomic_store(flg + g * 64 + slice * 4 + wv, (uint32_t)(t + 1),
                         __ATOMIC_RELAXED, __HIP_MEMORY_SCOPE_AGENT);

    // ---- prefetch x_{t+1} + edges_{t+1} (after publish: off the critical chain) ----
    if (t < TT - 1){
      const int r = tid >> 3, c8 = (tid & 7) * 32;
      const int node = nodes[(t + 1) * DDIM + d0 + r];
      unsigned short* dst = &xs[(t + 1) & 1][r * LSTR + c8];
      if (fdt){
        const uint4v* s = (const uint4v*)((const unsigned short*)emb + (size_t)node * 256 + c8);
        uint4v rv[4];
        #pragma unroll
        for (int j = 0; j < 4; ++j) rv[j] = s[j];
        #pragma unroll
        for (int j = 0; j < 4; ++j) ((uint4v*)dst)[j] = rv[j];
      } else {
        const float* s = (const float*)emb + (size_t)node * 256 + c8;
        float4v rv[8];
        #pragma unroll
        for (int j = 0; j < 8; ++j) rv[j] = ((const float4v*)s)[j];
        #pragma unroll
        for (int q = 0; q < 4; ++q){
          short8 v;
          #pragma unroll
          for (int j = 0; j < 8; ++j){ const int e2 = q*8+j; v[j] = (short)f2bf(rv[e2>>2][e2&3]); }
          *(short8*)&dst[q * 8] = v;
        }
      }
      const int base = (t + 1) * DDIM + d0 + rowb;
      if (efmt == 0){      for (int r2 = 0; r2 < 4; ++r2) ef[r2] = edges[base + r2] != 0; }
      else if (efmt == 1){ for (int r2 = 0; r2 < 4; ++r2) ef[r2] = ((const int*)edges)[base + r2] != 0; }
      else if (efmt == 3){ for (int r2 = 0; r2 < 4; ++r2) ef[r2] = ((const unsigned short*)edges)[base + r2] != 0; }
      else {               for (int r2 = 0; r2 < 4; ++r2) ef[r2] = ((const float*)edges)[base + r2] != 0.0f; }
    }

    __syncthreads();   // B2: xs[t+1] ready; hstg reads done before next gather
  }

  // ---- epilogue (slice 0): out[254] from gv (h_255), then gather h_256 for
  //      out[255] and the duplicated h_final row ----
  if (slice == 0){
    if (fdt){
      uint64_t* od = (uint64_t*)((unsigned short*)out + (size_t)254 * 131072
                                 + (size_t)(d0 + grow) * 256) + gchk;
      #pragma unroll
      for (int k = 0; k < 8; ++k) od[k * 8] = gv[k];
    } else {
      float* ob = (float*)out + (size_t)254 * 131072 + (size_t)(d0 + grow) * 256 + gchk * 4;
      #pragma unroll
      for (int k = 0; k < 8; ++k){
        float4v f;
        #pragma unroll
        for (int j = 0; j < 4; ++j) f[j] = bf2f((unsigned short)(gv[k] >> (16 * j)));
        *(float4v*)(ob + k * 32) = f;
      }
    }

    const uint32_t* fp = flg + g * 64 + lane;
    uint32_t fv = __hip_atomic_load(fp, __ATOMIC_RELAXED, __HIP_MEMORY_SCOPE_AGENT);
    int guard = 0;
    while (__ballot(fv < 256u) != 0ull){
      __builtin_amdgcn_s_sleep(1);
      fv = __hip_atomic_load(fp, __ATOMIC_RELAXED, __HIP_MEMORY_SCOPE_AGENT);
      if (++guard > (1 << 17)) break;
    }
    __atomic_signal_fence(__ATOMIC_SEQ_CST);
    const uint64_t* src = (const uint64_t*)(xb + /* buf 256&1=0 */ (size_t)(d0 + grow) * 256) + gchk;
    uint64_t ev[8];
    #pragma unroll
    for (int k = 0; k < 8; ++k)
      ev[k] = __hip_atomic_load(src + k * 8, __ATOMIC_RELAXED, __HIP_MEMORY_SCOPE_AGENT);
    if (fdt){
      unsigned short* o16 = (unsigned short*)out;
      uint64_t* o1 = (uint64_t*)(o16 + (size_t)255 * 131072 + (size_t)(d0 + grow) * 256) + gchk;
      uint64_t* o2 = (uint64_t*)(o16 + (size_t)256 * 131072 + (size_t)(d0 + grow) * 256) + gchk;
      #pragma unroll
      for (int k = 0; k < 8; ++k){ o1[k * 8] = ev[k]; o2[k * 8] = ev[k]; }
    } else {
      float* o1 = (float*)out + (size_t)255 * 131072 + (size_t)(d0 + grow) * 256 + gchk * 4;
      float* o2 = (float*)out + (size_t)256 * 131072 + (size_t)(d0 + grow) * 256 + gchk * 4;
      #pragma unroll
      for (int k = 0; k < 8; ++k){
        float4v f;
        #pragma unroll
        for (int j = 0; j < 4; ++j) f[j] = bf2f((unsigned short)(ev[k] >> (16 * j)));
        *(float4v*)(o1 + k * 32) = f;
        *(float4v*)(o2 + k * 32) = f;
      }
    }
  }
}

extern "C" void kernel_launch(void* const* d_in, const int* in_sizes, int n_in,
                              void* d_out, int out_size, void* d_ws, size_t ws_size,
                              hipStream_t stream)
{
  const int*           nodes = (const int*)d_in[0];
  const unsigned char* edges = (const unsigned char*)d_in[1];
  const unsigned char* hinit = (const unsigned char*)d_in[2];
  const unsigned char* emb   = (const unsigned char*)d_in[3];
  const unsigned char* cWih  = (const unsigned char*)d_in[4];
  const unsigned char* cWhh  = (const unsigned char*)d_in[5];
  const unsigned char* cbih  = (const unsigned char*)d_in[6];
  const unsigned char* cbhh  = (const unsigned char*)d_in[7];
  const unsigned char* sWih  = (const unsigned char*)d_in[8];
  const unsigned char* sWhh  = (const unsigned char*)d_in[9];
  const unsigned char* sbih  = (const unsigned char*)d_in[10];
  const unsigned char* sbhh  = (const unsigned char*)d_in[11];
  (void)in_sizes; (void)n_in; (void)out_size; (void)ws_size;

  // zero flag region (ws re-poisoned 0xAA before every launch)
  hipMemsetAsync(d_ws, 0, 8192, stream);

  treernn_main<<<dim3(256), dim3(256), 0, stream>>>(
      nodes, edges, hinit, emb, cWih, cWhh, cbih, cbhh, sWih, sWhh, sbih, sbhh,
      (unsigned char*)d_out, (unsigned char*)d_ws);
}